// Round 3
// baseline (583.939 us; speedup 1.0000x reference)
//
#include <hip/hip_runtime.h>
#include <math.h>

#define B_  16
#define N_  1024
#define L_  7
#define D_  512
#define H_  8
#define HD_ 64
#define BN_ (B_ * N_)

typedef __attribute__((ext_vector_type(4))) float f32x4;
typedef __attribute__((ext_vector_type(8))) short bf16x8;

__device__ __forceinline__ unsigned short f2bf(float f) {
  unsigned int u = __float_as_uint(f);
  u += 0x7fffu + ((u >> 16) & 1u);
  return (unsigned short)(u >> 16);
}
__device__ __forceinline__ unsigned int pack2(float lo, float hi) {
  return (unsigned int)f2bf(lo) | ((unsigned int)f2bf(hi) << 16);
}
__device__ __forceinline__ void load_lds16(const unsigned short* g, unsigned short* s) {
  __builtin_amdgcn_global_load_lds(
      (const __attribute__((address_space(1))) void*)g,
      (__attribute__((address_space(3))) void*)s, 16, 0, 0);
}

// ---------------------------------------------------------------------------
// f32 -> bf16 cast, 8 elems/thread
// ---------------------------------------------------------------------------
__global__ __launch_bounds__(256)
void cast_bf16_kernel(const float* __restrict__ src, unsigned short* __restrict__ dst,
                      int n8) {
  const int i = blockIdx.x * 256 + threadIdx.x;
  if (i >= n8) return;
  const float4 a = ((const float4*)src)[2 * i];
  const float4 b = ((const float4*)src)[2 * i + 1];
  uint4 o;
  o.x = pack2(a.x, a.y); o.y = pack2(a.z, a.w);
  o.z = pack2(b.x, b.y); o.w = pack2(b.z, b.w);
  ((uint4*)dst)[i] = o;
}

// 4 weight matrices (512x512) cast in one launch; blockIdx.y selects tensor
__global__ __launch_bounds__(256)
void cast_w4_kernel(const float* __restrict__ w0, const float* __restrict__ w1,
                    const float* __restrict__ w2, const float* __restrict__ w3,
                    unsigned short* __restrict__ o0, unsigned short* __restrict__ o1,
                    unsigned short* __restrict__ o2, unsigned short* __restrict__ o3) {
  const int y = blockIdx.y;
  const float* src = (y == 0) ? w0 : (y == 1) ? w1 : (y == 2) ? w2 : w3;
  unsigned short* dst = (y == 0) ? o0 : (y == 1) ? o1 : (y == 2) ? o2 : o3;
  const int i = blockIdx.x * 256 + threadIdx.x;   // D_*D_/8 = 32768
  const float4 a = ((const float4*)src)[2 * i];
  const float4 b = ((const float4*)src)[2 * i + 1];
  uint4 o;
  o.x = pack2(a.x, a.y); o.y = pack2(a.z, a.w);
  o.z = pack2(b.x, b.y); o.w = pack2(b.z, b.w);
  ((uint4*)dst)[i] = o;
}

// ---------------------------------------------------------------------------
// lag softmax + aggregation, bf16 output. 8 elems/thread.
// ---------------------------------------------------------------------------
__global__ __launch_bounds__(256)
void lag_agg_bf16_kernel(const float* __restrict__ lf, const float* __restrict__ lw,
                         unsigned short* __restrict__ out) {
  const int i = blockIdx.x * 256 + threadIdx.x;   // over BN_*D_/8
  float wv[L_];
  float m = -INFINITY;
#pragma unroll
  for (int l = 0; l < L_; ++l) { wv[l] = lw[l]; m = fmaxf(m, wv[l]); }
  float s = 0.f;
#pragma unroll
  for (int l = 0; l < L_; ++l) { wv[l] = __expf(wv[l] - m); s += wv[l]; }
  const float inv = 1.f / s;

  const int d8 = i & (D_ / 8 - 1);
  const int bn = i >> 6;
  const float* src = lf + (size_t)bn * (L_ * D_) + d8 * 8;
  float acc[8] = {};
#pragma unroll
  for (int l = 0; l < L_; ++l) {
    const float4 v0 = *(const float4*)(src + l * D_);
    const float4 v1 = *(const float4*)(src + l * D_ + 4);
    const float wl = wv[l] * inv;
    acc[0] += v0.x * wl; acc[1] += v0.y * wl; acc[2] += v0.z * wl; acc[3] += v0.w * wl;
    acc[4] += v1.x * wl; acc[5] += v1.y * wl; acc[6] += v1.z * wl; acc[7] += v1.w * wl;
  }
  uint4 o;
  o.x = pack2(acc[0], acc[1]); o.y = pack2(acc[2], acc[3]);
  o.z = pack2(acc[4], acc[5]); o.w = pack2(acc[6], acc[7]);
  ((uint4*)out)[i] = o;
}

// ---------------------------------------------------------------------------
// bf16 MFMA GEMM with 2-phase double-buffered staging.
// C[M,512] = A[M,512] @ W[512,512]^T + bias. 128x128 tile, BK=64, 4 waves.
// Per-iter: barrier (tile t staged; prev LDS reads done) -> issue async stage
// of t+1 (global_load_lds, overlaps with compute) -> ds_read+MFMA on t.
// LDS 64 KB (2 buf) -> 2 blocks/CU = grid-limited residency, unchanged.
// mode 0: bf16 row-major; mode 1: bf16 V^T [(b*8+h)*64+d][1024]; mode 2: f32.
// ---------------------------------------------------------------------------
struct GJob {
  const unsigned short* A;
  const unsigned short* W;
  const float* bias;
  void* C;
  int mode;
};

__global__ __launch_bounds__(256)
void gemm_dbuf_kernel(GJob j0, GJob j1, GJob j2) {
  const GJob j = (blockIdx.z == 0) ? j0 : (blockIdx.z == 1) ? j1 : j2;
  __shared__ unsigned short As[2 * 128 * 64];
  __shared__ unsigned short Bs[2 * 128 * 64];
  const int t = threadIdx.x;
  const int w = t >> 6, l = t & 63;
  const int wm = w >> 1, wn = w & 1;
  const int lc = l & 15, lg = l >> 4;
  const int m0 = blockIdx.y << 7, n0 = blockIdx.x << 7;
  const int srow = l >> 3, sc = l & 7;
  const unsigned short* A = j.A;
  const unsigned short* W = j.W;

  f32x4 acc[4][4];
#pragma unroll
  for (int i = 0; i < 4; ++i)
#pragma unroll
    for (int jj = 0; jj < 4; ++jj)
#pragma unroll
      for (int e = 0; e < 4; ++e) acc[i][jj][e] = 0.f;

  // prologue: stage k0=0 into buf 0
#pragma unroll
  for (int i = 0; i < 4; ++i) {
    const int rb = (w << 5) + (i << 3);
    const int row = rb + srow;
    const int c = sc ^ (row & 7);
    load_lds16(A + (size_t)(m0 + row) * D_ + (c << 3), As + rb * 64);
    load_lds16(W + (size_t)(n0 + row) * D_ + (c << 3), Bs + rb * 64);
  }

  int cur = 0;
  for (int k0 = 0; k0 < D_; k0 += 64) {
    __syncthreads();                     // tile (k0) staged; prev reads done
    if (k0 + 64 < D_) {                  // async stage of next tile
      unsigned short* An = As + ((cur ^ 1) << 13);
      unsigned short* Bn = Bs + ((cur ^ 1) << 13);
#pragma unroll
      for (int i = 0; i < 4; ++i) {
        const int rb = (w << 5) + (i << 3);
        const int row = rb + srow;
        const int c = sc ^ (row & 7);
        load_lds16(A + (size_t)(m0 + row) * D_ + k0 + 64 + (c << 3), An + rb * 64);
        load_lds16(W + (size_t)(n0 + row) * D_ + k0 + 64 + (c << 3), Bn + rb * 64);
      }
    }
    const unsigned short* Ac = As + (cur << 13);
    const unsigned short* Bc = Bs + (cur << 13);
#pragma unroll
    for (int kb = 0; kb < 2; ++kb) {
      bf16x8 af[4], bfr[4];
#pragma unroll
      for (int mi = 0; mi < 4; ++mi) {
        const int row = (wm << 6) + (mi << 4) + lc;
        const int pos = ((kb << 2) + lg) ^ (row & 7);
        af[mi] = *(const bf16x8*)(Ac + row * 64 + (pos << 3));
      }
#pragma unroll
      for (int ni = 0; ni < 4; ++ni) {
        const int row = (wn << 6) + (ni << 4) + lc;
        const int pos = ((kb << 2) + lg) ^ (row & 7);
        bfr[ni] = *(const bf16x8*)(Bc + row * 64 + (pos << 3));
      }
#pragma unroll
      for (int mi = 0; mi < 4; ++mi)
#pragma unroll
        for (int ni = 0; ni < 4; ++ni)
          acc[mi][ni] = __builtin_amdgcn_mfma_f32_16x16x32_bf16(
              af[mi], bfr[ni], acc[mi][ni], 0, 0, 0);
    }
    cur ^= 1;
  }

  const int mode = j.mode;
#pragma unroll
  for (int ni = 0; ni < 4; ++ni) {
    const int n = n0 + (wn << 6) + (ni << 4) + lc;
    const float bv = j.bias[n];
#pragma unroll
    for (int mi = 0; mi < 4; ++mi) {
      const int mb = m0 + (wm << 6) + (mi << 4) + (lg << 2);
      if (mode == 2) {
        float* O = (float*)j.C;
#pragma unroll
        for (int e = 0; e < 4; ++e)
          O[(size_t)(mb + e) * D_ + n] = acc[mi][ni][e] + bv;
      } else if (mode == 0) {
        unsigned short* O = (unsigned short*)j.C;
#pragma unroll
        for (int e = 0; e < 4; ++e)
          O[(size_t)(mb + e) * D_ + n] = f2bf(acc[mi][ni][e] + bv);
      } else {  // V^T: Vt[(b*8+h)*64 + d][token]
        unsigned short* O = (unsigned short*)j.C;
        const int bb = mb >> 10, hh = n >> 6, d = n & 63;
        uint2 pk;
        pk.x = pack2(acc[mi][ni][0] + bv, acc[mi][ni][1] + bv);
        pk.y = pack2(acc[mi][ni][2] + bv, acc[mi][ni][3] + bv);
        *(uint2*)(O + ((size_t)((bb << 3) + hh) * HD_ + d) * N_ + (mb & 1023)) = pk;
      }
    }
  }
}

// ---------------------------------------------------------------------------
// bf16 MFMA flash attention, 2-phase double-buffered K/V staging.
// Swapped S^T = mfma(K, Q): lane owns one q-row -> lane-local softmax.
// Q-frags hoisted out of the kt loop; the dead Qs region is reused as a
// wave-private P_lds: PV B-frag (= P[q=lc][kv=32kb+8lg..+7], 16 contiguous
// bytes, chunk-XOR swizzled) is written with 4 ds_write_b64 and read back
// with 2 ds_read_b128 per tile — replaces 16 ds_bpermute + selects.
// Intra-wave LDS ops are in-order: no barrier needed for the P round-trip.
// LDS 40 KB -> 4 blocks/CU.
// ---------------------------------------------------------------------------
__global__ __launch_bounds__(256)
void attn_bf16_kernel(const unsigned short* __restrict__ Q,
                      const unsigned short* __restrict__ K,
                      const unsigned short* __restrict__ Vt,
                      const float* __restrict__ adj,
                      unsigned short* __restrict__ Out) {
  const int bh = blockIdx.y, b = bh >> 3, h = bh & 7;
  const int q0 = blockIdx.x << 6;
  const int t = threadIdx.x, w = t >> 6, l = t & 63;
  const int lc = l & 15, lg = l >> 4;
  __shared__ unsigned short Qs[64 * 64];        // reused as P_lds after hoist
  __shared__ unsigned short Ks[2 * 64 * 64];
  __shared__ unsigned short Vs[2 * 64 * 64];
  const unsigned short* Qg = Q + (size_t)b * N_ * D_ + h * HD_;
  const unsigned short* Kg = K + (size_t)b * N_ * D_ + h * HD_;
  const unsigned short* Vg = Vt + (size_t)((b << 3) + h) * HD_ * N_;

  // prologue: stage Q tile + K/V tile 0 (buf 0)
#pragma unroll
  for (int i = 0; i < 2; ++i) {
    const int rb = (w << 4) + (i << 3);
    const int row = rb + (l >> 3);
    const int c = (l & 7) ^ (row & 7);
    load_lds16(Qg + (size_t)(q0 + row) * D_ + (c << 3), Qs + rb * 64);
    load_lds16(Kg + (size_t)row * D_ + (c << 3), Ks + rb * 64);
    load_lds16(Vg + (size_t)row * N_ + (c << 3), Vs + rb * 64);
  }
  __syncthreads();

  // hoist Q-frags (wave reads only its own 16 rows)
  bf16x8 qf[2];
#pragma unroll
  for (int kb = 0; kb < 2; ++kb) {
    const int row = (w << 4) + lc;
    const int pos = ((kb << 2) + lg) ^ (row & 7);
    qf[kb] = *(const bf16x8*)(Qs + row * 64 + (pos << 3));
  }

  float m_r = -INFINITY, l_r = 0.f;
  f32x4 o[4];
#pragma unroll
  for (int di = 0; di < 4; ++di)
#pragma unroll
    for (int e = 0; e < 4; ++e) o[di][e] = 0.f;
  const int myq = q0 + (w << 4) + lc;
  unsigned short* Pw = Qs + (w << 10);          // wave-private 16x64 region

  int cur = 0;
  for (int kt = 0; kt < 16; ++kt) {
    if (kt) __syncthreads();            // tile kt staged; prev reads done
    const int kv0 = kt << 6;
    if (kt < 15) {                      // async stage of tile kt+1
      unsigned short* Kn = Ks + ((cur ^ 1) << 12);
      unsigned short* Vn = Vs + ((cur ^ 1) << 12);
#pragma unroll
      for (int i = 0; i < 2; ++i) {
        const int rb = (w << 4) + (i << 3);
        const int row = rb + (l >> 3);
        const int c = (l & 7) ^ (row & 7);
        load_lds16(Kg + (size_t)(kv0 + 64 + row) * D_ + (c << 3), Kn + rb * 64);
        load_lds16(Vg + (size_t)row * N_ + kv0 + 64 + (c << 3), Vn + rb * 64);
      }
    }
    f32x4 aj[4];
#pragma unroll
    for (int ni = 0; ni < 4; ++ni)
      aj[ni] = *(const f32x4*)(adj + (size_t)myq * N_ + kv0 + (ni << 4) + (lg << 2));

    const unsigned short* Kc = Ks + (cur << 12);
    const unsigned short* Vc = Vs + (cur << 12);

    // S^T[kv][q]: frag ni covers kv 16ni..+15; lane holds q=lc, kv=4lg+e
    f32x4 st[4];
#pragma unroll
    for (int ni = 0; ni < 4; ++ni)
#pragma unroll
      for (int e = 0; e < 4; ++e) st[ni][e] = 0.f;
#pragma unroll
    for (int ni = 0; ni < 4; ++ni)
#pragma unroll
      for (int kb = 0; kb < 2; ++kb) {
        const int row = (ni << 4) + lc;
        const int pos = ((kb << 2) + lg) ^ (row & 7);
        const bf16x8 kf = *(const bf16x8*)(Kc + row * 64 + (pos << 3));
        st[ni] = __builtin_amdgcn_mfma_f32_16x16x32_bf16(kf, qf[kb], st[ni], 0, 0, 0);
      }

    // online softmax: lane-local 16 vals + cross-group shfl_xor(16,32)
    float tmax = -INFINITY;
#pragma unroll
    for (int ni = 0; ni < 4; ++ni)
#pragma unroll
      for (int e = 0; e < 4; ++e) {
        const float v = st[ni][e] * 0.125f + 0.5f * aj[ni][e];
        st[ni][e] = v;
        tmax = fmaxf(tmax, v);
      }
    tmax = fmaxf(tmax, __shfl_xor(tmax, 16));
    tmax = fmaxf(tmax, __shfl_xor(tmax, 32));
    const float mnew = fmaxf(m_r, tmax);
    const float alpha = __expf(m_r - mnew);     // exp(-inf)=0 first tile
    float ts = 0.f;
#pragma unroll
    for (int ni = 0; ni < 4; ++ni)
#pragma unroll
      for (int e = 0; e < 4; ++e) {
        const float p = __expf(st[ni][e] - mnew);
        st[ni][e] = p;
        ts += p;
      }
    ts += __shfl_xor(ts, 16);
    ts += __shfl_xor(ts, 32);
    l_r = l_r * alpha + ts;
    m_r = mnew;
#pragma unroll
    for (int di = 0; di < 4; ++di)
#pragma unroll
      for (int e = 0; e < 4; ++e) o[di][e] *= alpha;

    // P -> wave-private LDS: lane holds kv=16ni+4lg+{0..3} at row q=lc.
    // chunk = kv>>3 = 2ni+(lg>>1), XOR-swizzled by (lc&7); 8B write per ni.
#pragma unroll
    for (int ni = 0; ni < 4; ++ni) {
      uint2 pr;
      pr.x = pack2(st[ni][0], st[ni][1]);
      pr.y = pack2(st[ni][2], st[ni][3]);
      const int schunk = (2 * ni + (lg >> 1)) ^ (lc & 7);
      *(uint2*)(Pw + lc * 64 + (schunk << 3) + ((lg & 1) << 2)) = pr;
    }

    // PV: O^T[d][q] += V^T-frag x P-frag; B-frag = P[q=lc][32kb+8lg..+7]
#pragma unroll
    for (int kb = 0; kb < 2; ++kb) {
      const int rchunk = ((kb << 2) + lg) ^ (lc & 7);
      const bf16x8 pb = *(const bf16x8*)(Pw + lc * 64 + (rchunk << 3));
#pragma unroll
      for (int di = 0; di < 4; ++di) {
        const int row = (di << 4) + lc;
        const int pos = ((kb << 2) + lg) ^ (row & 7);
        const bf16x8 vf = *(const bf16x8*)(Vc + row * 64 + (pos << 3));
        o[di] = __builtin_amdgcn_mfma_f32_16x16x32_bf16(vf, pb, o[di], 0, 0, 0);
      }
    }
    cur ^= 1;
  }

  // epilogue: lane owns q = myq, d = 16di + 4lg + e
  const float inv = 1.f / l_r;
  unsigned short* Ob = Out + (size_t)(b * N_ + q0 + (w << 4) + lc) * D_ + h * HD_;
#pragma unroll
  for (int di = 0; di < 4; ++di) {
    uint2 pk;
    pk.x = pack2(o[di][0] * inv, o[di][1] * inv);
    pk.y = pack2(o[di][2] * inv, o[di][3] * inv);
    *(uint2*)(Ob + (di << 4) + (lg << 2)) = pk;
  }
}

// ---------------------------------------------------------------------------
// in-place residual + LayerNorm, one wave per 512-float row (f32)
// ---------------------------------------------------------------------------
__global__ __launch_bounds__(256)
void ln_kernel(float* __restrict__ Y, const float* __restrict__ Xr,
               const float* __restrict__ g, const float* __restrict__ bta) {
  const int row  = (blockIdx.x << 2) + (threadIdx.x >> 6);
  const int lane = threadIdx.x & 63;
  float* yrow = Y + (size_t)row * D_;
  const float* xrow = Xr + (size_t)row * D_;
  const int c0 = lane << 3;

  const float4 y0 = *(const float4*)(yrow + c0);
  const float4 y1 = *(const float4*)(yrow + c0 + 4);
  const float4 r0 = *(const float4*)(xrow + c0);
  const float4 r1 = *(const float4*)(xrow + c0 + 4);
  float x[8] = {y0.x + r0.x, y0.y + r0.y, y0.z + r0.z, y0.w + r0.w,
                y1.x + r1.x, y1.y + r1.y, y1.z + r1.z, y1.w + r1.w};

  float sum = 0.f;
#pragma unroll
  for (int u = 0; u < 8; ++u) sum += x[u];
#pragma unroll
  for (int off = 32; off >= 1; off >>= 1) sum += __shfl_xor(sum, off);
  const float mu = sum * (1.f / D_);

  float vs = 0.f;
#pragma unroll
  for (int u = 0; u < 8; ++u) { const float d = x[u] - mu; vs += d * d; }
#pragma unroll
  for (int off = 32; off >= 1; off >>= 1) vs += __shfl_xor(vs, off);
  const float var = vs * (1.f / D_) + 1e-5f;
  float rinv = rsqrtf(var);
  rinv = rinv * (1.5f - 0.5f * var * rinv * rinv);   // Newton refine

  const float4 g0 = *(const float4*)(g + c0);
  const float4 g1 = *(const float4*)(g + c0 + 4);
  const float4 b0 = *(const float4*)(bta + c0);
  const float4 b1 = *(const float4*)(bta + c0 + 4);
  float4 o0, o1;
  o0.x = (x[0] - mu) * rinv * g0.x + b0.x;
  o0.y = (x[1] - mu) * rinv * g0.y + b0.y;
  o0.z = (x[2] - mu) * rinv * g0.z + b0.z;
  o0.w = (x[3] - mu) * rinv * g0.w + b0.w;
  o1.x = (x[4] - mu) * rinv * g1.x + b1.x;
  o1.y = (x[5] - mu) * rinv * g1.y + b1.y;
  o1.z = (x[6] - mu) * rinv * g1.z + b1.z;
  o1.w = (x[7] - mu) * rinv * g1.w + b1.w;
  *(float4*)(yrow + c0) = o0;
  *(float4*)(yrow + c0 + 4) = o1;
}

extern "C" void kernel_launch(void* const* d_in, const int* in_sizes, int n_in,
                              void* d_out, int out_size, void* d_ws, size_t ws_size,
                              hipStream_t stream) {
  const float* cur = (const float*)d_in[0];
  const float* lf  = (const float*)d_in[1];
  const float* lw  = (const float*)d_in[2];
  const float* Wq  = (const float*)d_in[3];
  const float* bq  = (const float*)d_in[4];
  const float* Wk  = (const float*)d_in[5];
  const float* bk  = (const float*)d_in[6];
  const float* Wv  = (const float*)d_in[7];
  const float* bv  = (const float*)d_in[8];
  const float* Wo  = (const float*)d_in[9];
  const float* bo  = (const float*)d_in[10];
  const float* adj = (const float*)d_in[11];
  const float* lng = (const float*)d_in[12];
  const float* lnb = (const float*)d_in[13];
  float* out = (float*)d_out;

  const size_t NE = (size_t)BN_ * D_;   // 8388608 elements
  unsigned short* wsb   = (unsigned short*)d_ws;
  unsigned short* curb  = wsb;
  unsigned short* laggb = wsb + NE;
  unsigned short* Qb    = wsb + 2 * NE;
  unsigned short* Kb    = wsb + 3 * NE;
  unsigned short* Vtb   = wsb + 4 * NE;
  unsigned short* attnb = wsb + 5 * NE;
  unsigned short* Wqb   = wsb + 6 * NE;
  unsigned short* Wkb   = Wqb + (size_t)D_ * D_;
  unsigned short* Wvb   = Wkb + (size_t)D_ * D_;
  unsigned short* Wob   = Wvb + (size_t)D_ * D_;

  cast_bf16_kernel<<<BN_ * D_ / 8 / 256, 256, 0, stream>>>(cur, curb, BN_ * D_ / 8);
  cast_w4_kernel<<<dim3(D_ * D_ / 8 / 256, 4), 256, 0, stream>>>(
      Wq, Wk, Wv, Wo, Wqb, Wkb, Wvb, Wob);
  lag_agg_bf16_kernel<<<BN_ * D_ / 8 / 256, 256, 0, stream>>>(lf, lw, laggb);

  GJob jq{curb,  Wqb, bq, (void*)Qb,  0};
  GJob jk{laggb, Wkb, bk, (void*)Kb,  0};
  GJob jv{laggb, Wvb, bv, (void*)Vtb, 1};
  gemm_dbuf_kernel<<<dim3(D_ / 128, BN_ / 128, 3), 256, 0, stream>>>(jq, jk, jv);

  attn_bf16_kernel<<<dim3(N_ / 64, B_ * H_), 256, 0, stream>>>(Qb, Kb, Vtb, adj, attnb);

  GJob jo{attnb, Wob, bo, (void*)out, 2};
  gemm_dbuf_kernel<<<dim3(D_ / 128, BN_ / 128, 1), 256, 0, stream>>>(jo, jo, jo);

  ln_kernel<<<BN_ / 4, 256, 0, stream>>>(out, cur, lng, lnb);
}

// Round 4
// 547.747 us; speedup vs baseline: 1.0661x; 1.0661x over previous
//
#include <hip/hip_runtime.h>
#include <math.h>

#define B_  16
#define N_  1024
#define L_  7
#define D_  512
#define H_  8
#define HD_ 64
#define BN_ (B_ * N_)

#define LOG2E_ 1.44269504088896f
#define QSCALE_ (0.125f * LOG2E_)
#define ADJSCALE_ (0.5f * LOG2E_)

typedef __attribute__((ext_vector_type(4))) float f32x4;
typedef __attribute__((ext_vector_type(8))) short bf16x8;

__device__ __forceinline__ unsigned short f2bf(float f) {
  unsigned int u = __float_as_uint(f);
  u += 0x7fffu + ((u >> 16) & 1u);
  return (unsigned short)(u >> 16);
}
__device__ __forceinline__ unsigned int pack2(float lo, float hi) {
  return (unsigned int)f2bf(lo) | ((unsigned int)f2bf(hi) << 16);
}
__device__ __forceinline__ void load_lds16(const unsigned short* g, unsigned short* s) {
  __builtin_amdgcn_global_load_lds(
      (const __attribute__((address_space(1))) void*)g,
      (__attribute__((address_space(3))) void*)s, 16, 0, 0);
}
#if __has_builtin(__builtin_amdgcn_exp2f)
__device__ __forceinline__ float exp2_(float x) { return __builtin_amdgcn_exp2f(x); }
#else
__device__ __forceinline__ float exp2_(float x) { return exp2f(x); }
#endif

// ---------------------------------------------------------------------------
// prep: [0,4096) lag softmax+agg -> laggb ; [4096,8192) cast cur -> curb ;
//       [8192,8704) adjh = adj * 0.5*log2e (f32)
// ---------------------------------------------------------------------------
__global__ __launch_bounds__(256)
void prep_kernel(const float* __restrict__ lf, const float* __restrict__ lw,
                 const float* __restrict__ cur, const float* __restrict__ adj,
                 unsigned short* __restrict__ laggb, unsigned short* __restrict__ curb,
                 float* __restrict__ adjh) {
  const int bid = blockIdx.x;
  if (bid < 4096) {
    const int i = bid * 256 + threadIdx.x;        // over BN_*D_/8
    float wv[L_];
    float m = -INFINITY;
#pragma unroll
    for (int l = 0; l < L_; ++l) { wv[l] = lw[l]; m = fmaxf(m, wv[l]); }
    float s = 0.f;
#pragma unroll
    for (int l = 0; l < L_; ++l) { wv[l] = __expf(wv[l] - m); s += wv[l]; }
    const float inv = 1.f / s;
    const int d8 = i & (D_ / 8 - 1);
    const int bn = i >> 6;
    const float* src = lf + (size_t)bn * (L_ * D_) + d8 * 8;
    float acc[8] = {};
#pragma unroll
    for (int l = 0; l < L_; ++l) {
      const float4 v0 = *(const float4*)(src + l * D_);
      const float4 v1 = *(const float4*)(src + l * D_ + 4);
      const float wl = wv[l] * inv;
      acc[0] += v0.x * wl; acc[1] += v0.y * wl; acc[2] += v0.z * wl; acc[3] += v0.w * wl;
      acc[4] += v1.x * wl; acc[5] += v1.y * wl; acc[6] += v1.z * wl; acc[7] += v1.w * wl;
    }
    uint4 o;
    o.x = pack2(acc[0], acc[1]); o.y = pack2(acc[2], acc[3]);
    o.z = pack2(acc[4], acc[5]); o.w = pack2(acc[6], acc[7]);
    ((uint4*)laggb)[i] = o;
  } else if (bid < 8192) {
    const int i = (bid - 4096) * 256 + threadIdx.x;
    const float4 a = ((const float4*)cur)[2 * i];
    const float4 b = ((const float4*)cur)[2 * i + 1];
    uint4 o;
    o.x = pack2(a.x, a.y); o.y = pack2(a.z, a.w);
    o.z = pack2(b.x, b.y); o.w = pack2(b.z, b.w);
    ((uint4*)curb)[i] = o;
  } else {
    const int i = (bid - 8192) * 256 + threadIdx.x;  // over N_*N_/8
    float4 a = ((const float4*)adj)[2 * i];
    float4 b = ((const float4*)adj)[2 * i + 1];
    a.x *= ADJSCALE_; a.y *= ADJSCALE_; a.z *= ADJSCALE_; a.w *= ADJSCALE_;
    b.x *= ADJSCALE_; b.y *= ADJSCALE_; b.z *= ADJSCALE_; b.w *= ADJSCALE_;
    ((float4*)adjh)[2 * i] = a;
    ((float4*)adjh)[2 * i + 1] = b;
  }
}

// 4 weight matrices (512x512) cast in one launch; blockIdx.y selects tensor
__global__ __launch_bounds__(256)
void cast_w4_kernel(const float* __restrict__ w0, const float* __restrict__ w1,
                    const float* __restrict__ w2, const float* __restrict__ w3,
                    unsigned short* __restrict__ o0, unsigned short* __restrict__ o1,
                    unsigned short* __restrict__ o2, unsigned short* __restrict__ o3) {
  const int y = blockIdx.y;
  const float* src = (y == 0) ? w0 : (y == 1) ? w1 : (y == 2) ? w2 : w3;
  unsigned short* dst = (y == 0) ? o0 : (y == 1) ? o1 : (y == 2) ? o2 : o3;
  const int i = blockIdx.x * 256 + threadIdx.x;
  const float4 a = ((const float4*)src)[2 * i];
  const float4 b = ((const float4*)src)[2 * i + 1];
  uint4 o;
  o.x = pack2(a.x, a.y); o.y = pack2(a.z, a.w);
  o.z = pack2(b.x, b.y); o.w = pack2(b.z, b.w);
  ((uint4*)dst)[i] = o;
}

// ---------------------------------------------------------------------------
// bf16 MFMA GEMM, single-buffered (R2 structure, 32 KB LDS -> 5 blocks/CU).
// C[M,512] = A @ W^T + bias, optional output scale (Q: 0.125*log2e fold).
// 128x128 tile, BK=64, 4 waves (2x2), 16x16x32 MFMA, chunk-XOR LDS swizzle.
// mode 0: bf16 row-major; mode 1: bf16 V^T [(b*8+h)*64+d][1024]; mode 2: f32.
// ---------------------------------------------------------------------------
struct GJob {
  const unsigned short* A;
  const unsigned short* W;
  const float* bias;
  void* C;
  int mode;
  float oscale;
};

__global__ __launch_bounds__(256)
void gemm_s_kernel(GJob j0, GJob j1, GJob j2) {
  const GJob j = (blockIdx.z == 0) ? j0 : (blockIdx.z == 1) ? j1 : j2;
  __shared__ unsigned short As[128 * 64];
  __shared__ unsigned short Bs[128 * 64];
  const int t = threadIdx.x;
  const int w = t >> 6, l = t & 63;
  const int wm = w >> 1, wn = w & 1;
  const int lc = l & 15, lg = l >> 4;
  const int m0 = blockIdx.y << 7, n0 = blockIdx.x << 7;
  const int srow = l >> 3, sc = l & 7;
  const unsigned short* A = j.A;
  const unsigned short* W = j.W;

  f32x4 acc[4][4];
#pragma unroll
  for (int i = 0; i < 4; ++i)
#pragma unroll
    for (int jj = 0; jj < 4; ++jj)
#pragma unroll
      for (int e = 0; e < 4; ++e) acc[i][jj][e] = 0.f;

  for (int k0 = 0; k0 < D_; k0 += 64) {
    __syncthreads();                     // prev iter LDS reads done
#pragma unroll
    for (int i = 0; i < 4; ++i) {
      const int rb = (w << 5) + (i << 3);
      const int row = rb + srow;
      const int c = sc ^ (row & 7);
      load_lds16(A + (size_t)(m0 + row) * D_ + k0 + (c << 3), As + rb * 64);
      load_lds16(W + (size_t)(n0 + row) * D_ + k0 + (c << 3), Bs + rb * 64);
    }
    __syncthreads();                     // drains vmcnt
#pragma unroll
    for (int kb = 0; kb < 2; ++kb) {
      bf16x8 af[4], bfr[4];
#pragma unroll
      for (int mi = 0; mi < 4; ++mi) {
        const int row = (wm << 6) + (mi << 4) + lc;
        const int pos = ((kb << 2) + lg) ^ (row & 7);
        af[mi] = *(const bf16x8*)(As + row * 64 + (pos << 3));
      }
#pragma unroll
      for (int ni = 0; ni < 4; ++ni) {
        const int row = (wn << 6) + (ni << 4) + lc;
        const int pos = ((kb << 2) + lg) ^ (row & 7);
        bfr[ni] = *(const bf16x8*)(Bs + row * 64 + (pos << 3));
      }
      __builtin_amdgcn_s_setprio(1);
#pragma unroll
      for (int mi = 0; mi < 4; ++mi)
#pragma unroll
        for (int ni = 0; ni < 4; ++ni)
          acc[mi][ni] = __builtin_amdgcn_mfma_f32_16x16x32_bf16(
              af[mi], bfr[ni], acc[mi][ni], 0, 0, 0);
      __builtin_amdgcn_s_setprio(0);
    }
  }

  const int mode = j.mode;
  const float osc = j.oscale;
#pragma unroll
  for (int ni = 0; ni < 4; ++ni) {
    const int n = n0 + (wn << 6) + (ni << 4) + lc;
    const float bv = j.bias[n];
#pragma unroll
    for (int mi = 0; mi < 4; ++mi) {
      const int mb = m0 + (wm << 6) + (mi << 4) + (lg << 2);
      if (mode == 2) {
        float* O = (float*)j.C;
#pragma unroll
        for (int e = 0; e < 4; ++e)
          O[(size_t)(mb + e) * D_ + n] = acc[mi][ni][e] + bv;
      } else if (mode == 0) {
        unsigned short* O = (unsigned short*)j.C;
#pragma unroll
        for (int e = 0; e < 4; ++e)
          O[(size_t)(mb + e) * D_ + n] = f2bf((acc[mi][ni][e] + bv) * osc);
      } else {  // V^T: Vt[(b*8+h)*64 + d][token]
        unsigned short* O = (unsigned short*)j.C;
        const int bb = mb >> 10, hh = n >> 6, d = n & 63;
        uint2 pk;
        pk.x = pack2(acc[mi][ni][0] + bv, acc[mi][ni][1] + bv);
        pk.y = pack2(acc[mi][ni][2] + bv, acc[mi][ni][3] + bv);
        *(uint2*)(O + ((size_t)((bb << 3) + hh) * HD_ + d) * N_ + (mb & 1023)) = pk;
      }
    }
  }
}

// ---------------------------------------------------------------------------
// bf16 MFMA flash attention, single-buffered K/V (24 KB LDS).
// Q pre-scaled by 0.125*log2e (folded in Q-GEMM); adjh = 0.5*log2e*adj.
// Softmax in exp2 domain (v_exp_f32 native), defer-max THR=8 (T13),
// setprio around MFMA clusters (T5). Swapped S^T = mfma(K,Q): lane owns one
// q-row -> lane-local softmax + 2 shfl_xor. Q-frags hoisted; dead Qs region
// reused as wave-private P_lds (4 ds_write_b64 + 2 ds_read_b128 per tile).
// ---------------------------------------------------------------------------
__global__ __launch_bounds__(256)
void attn_bf16_kernel(const unsigned short* __restrict__ Q,
                      const unsigned short* __restrict__ K,
                      const unsigned short* __restrict__ Vt,
                      const float* __restrict__ adjh,
                      unsigned short* __restrict__ Out) {
  const int bh = blockIdx.y, b = bh >> 3, h = bh & 7;
  const int q0 = blockIdx.x << 6;
  const int t = threadIdx.x, w = t >> 6, l = t & 63;
  const int lc = l & 15, lg = l >> 4;
  __shared__ unsigned short Qs[64 * 64];        // reused as P_lds after hoist
  __shared__ unsigned short Ks[64 * 64];
  __shared__ unsigned short Vs[64 * 64];
  const unsigned short* Qg = Q + (size_t)b * N_ * D_ + h * HD_;
  const unsigned short* Kg = K + (size_t)b * N_ * D_ + h * HD_;
  const unsigned short* Vg = Vt + (size_t)((b << 3) + h) * HD_ * N_;

#pragma unroll
  for (int i = 0; i < 2; ++i) {           // stage Q once
    const int rb = (w << 4) + (i << 3);
    const int row = rb + (l >> 3);
    const int c = (l & 7) ^ (row & 7);
    load_lds16(Qg + (size_t)(q0 + row) * D_ + (c << 3), Qs + rb * 64);
  }
  __syncthreads();

  bf16x8 qf[2];                           // hoist Q-frags (own 16 rows)
#pragma unroll
  for (int kb = 0; kb < 2; ++kb) {
    const int row = (w << 4) + lc;
    const int pos = ((kb << 2) + lg) ^ (row & 7);
    qf[kb] = *(const bf16x8*)(Qs + row * 64 + (pos << 3));
  }

  float m_r = -INFINITY, l_r = 0.f;
  f32x4 o[4];
#pragma unroll
  for (int di = 0; di < 4; ++di)
#pragma unroll
    for (int e = 0; e < 4; ++e) o[di][e] = 0.f;
  const int myq = q0 + (w << 4) + lc;
  unsigned short* Pw = Qs + (w << 10);    // wave-private 16x64 region

  for (int kt = 0; kt < 16; ++kt) {
    const int kv0 = kt << 6;
    __syncthreads();                      // prev tile reads done
#pragma unroll
    for (int i = 0; i < 2; ++i) {         // stage K (row-major), V^T (d-major)
      const int rb = (w << 4) + (i << 3);
      const int row = rb + (l >> 3);
      const int c = (l & 7) ^ (row & 7);
      load_lds16(Kg + (size_t)(kv0 + row) * D_ + (c << 3), Ks + rb * 64);
      load_lds16(Vg + (size_t)row * N_ + kv0 + (c << 3), Vs + rb * 64);
    }
    f32x4 aj[4];
#pragma unroll
    for (int ni = 0; ni < 4; ++ni)
      aj[ni] = *(const f32x4*)(adjh + (size_t)myq * N_ + kv0 + (ni << 4) + (lg << 2));
    __syncthreads();                      // staging complete

    // S^T[kv][q]: frag ni covers kv 16ni..+15; lane holds q=lc, kv=4lg+e
    f32x4 st[4];
#pragma unroll
    for (int ni = 0; ni < 4; ++ni)
#pragma unroll
      for (int e = 0; e < 4; ++e) st[ni][e] = 0.f;
    __builtin_amdgcn_s_setprio(1);
#pragma unroll
    for (int ni = 0; ni < 4; ++ni)
#pragma unroll
      for (int kb = 0; kb < 2; ++kb) {
        const int row = (ni << 4) + lc;
        const int pos = ((kb << 2) + lg) ^ (row & 7);
        const bf16x8 kf = *(const bf16x8*)(Ks + row * 64 + (pos << 3));
        st[ni] = __builtin_amdgcn_mfma_f32_16x16x32_bf16(kf, qf[kb], st[ni], 0, 0, 0);
      }
    __builtin_amdgcn_s_setprio(0);

    // exp2-domain online softmax; score bias is a single add (folds done)
    float tmax = -INFINITY;
#pragma unroll
    for (int ni = 0; ni < 4; ++ni)
#pragma unroll
      for (int e = 0; e < 4; ++e) {
        const float v = st[ni][e] + aj[ni][e];
        st[ni][e] = v;
        tmax = fmaxf(tmax, v);
      }
    tmax = fmaxf(tmax, __shfl_xor(tmax, 16));
    tmax = fmaxf(tmax, __shfl_xor(tmax, 32));
    if (!__all(tmax <= m_r + 8.f)) {      // defer-max: rescale only on growth
      const float mnew = fmaxf(m_r, tmax);
      const float alpha = exp2_(m_r - mnew);   // exp2(-inf)=0 first tile
      l_r *= alpha;
#pragma unroll
      for (int di = 0; di < 4; ++di)
#pragma unroll
        for (int e = 0; e < 4; ++e) o[di][e] *= alpha;
      m_r = mnew;
    }
    float ts = 0.f;
#pragma unroll
    for (int ni = 0; ni < 4; ++ni)
#pragma unroll
      for (int e = 0; e < 4; ++e) {
        const float p = exp2_(st[ni][e] - m_r);
        st[ni][e] = p;
        ts += p;
      }
    ts += __shfl_xor(ts, 16);
    ts += __shfl_xor(ts, 32);
    l_r += ts;

    // P -> wave-private LDS (chunk-XOR swizzled), 8B per ni
#pragma unroll
    for (int ni = 0; ni < 4; ++ni) {
      uint2 pr;
      pr.x = pack2(st[ni][0], st[ni][1]);
      pr.y = pack2(st[ni][2], st[ni][3]);
      const int schunk = (2 * ni + (lg >> 1)) ^ (lc & 7);
      *(uint2*)(Pw + lc * 64 + (schunk << 3) + ((lg & 1) << 2)) = pr;
    }

    // PV: O^T[d][q] += V^T-frag x P-frag; B-frag = P[q=lc][32kb+8lg..+7]
#pragma unroll
    for (int kb = 0; kb < 2; ++kb) {
      const int rchunk = ((kb << 2) + lg) ^ (lc & 7);
      const bf16x8 pb = *(const bf16x8*)(Pw + lc * 64 + (rchunk << 3));
      __builtin_amdgcn_s_setprio(1);
#pragma unroll
      for (int di = 0; di < 4; ++di) {
        const int row = (di << 4) + lc;
        const int pos = ((kb << 2) + lg) ^ (row & 7);
        const bf16x8 vf = *(const bf16x8*)(Vs + row * 64 + (pos << 3));
        o[di] = __builtin_amdgcn_mfma_f32_16x16x32_bf16(vf, pb, o[di], 0, 0, 0);
      }
      __builtin_amdgcn_s_setprio(0);
    }
  }

  const float inv = 1.f / l_r;
  unsigned short* Ob = Out + (size_t)(b * N_ + q0 + (w << 4) + lc) * D_ + h * HD_;
#pragma unroll
  for (int di = 0; di < 4; ++di) {
    uint2 pk;
    pk.x = pack2(o[di][0] * inv, o[di][1] * inv);
    pk.y = pack2(o[di][2] * inv, o[di][3] * inv);
    *(uint2*)(Ob + (di << 4) + (lg << 2)) = pk;
  }
}

// ---------------------------------------------------------------------------
// in-place residual + LayerNorm, one wave per 512-float row (f32)
// ---------------------------------------------------------------------------
__global__ __launch_bounds__(256)
void ln_kernel(float* __restrict__ Y, const float* __restrict__ Xr,
               const float* __restrict__ g, const float* __restrict__ bta) {
  const int row  = (blockIdx.x << 2) + (threadIdx.x >> 6);
  const int lane = threadIdx.x & 63;
  float* yrow = Y + (size_t)row * D_;
  const float* xrow = Xr + (size_t)row * D_;
  const int c0 = lane << 3;

  const float4 y0 = *(const float4*)(yrow + c0);
  const float4 y1 = *(const float4*)(yrow + c0 + 4);
  const float4 r0 = *(const float4*)(xrow + c0);
  const float4 r1 = *(const float4*)(xrow + c0 + 4);
  float x[8] = {y0.x + r0.x, y0.y + r0.y, y0.z + r0.z, y0.w + r0.w,
                y1.x + r1.x, y1.y + r1.y, y1.z + r1.z, y1.w + r1.w};

  float sum = 0.f;
#pragma unroll
  for (int u = 0; u < 8; ++u) sum += x[u];
#pragma unroll
  for (int off = 32; off >= 1; off >>= 1) sum += __shfl_xor(sum, off);
  const float mu = sum * (1.f / D_);

  float vs = 0.f;
#pragma unroll
  for (int u = 0; u < 8; ++u) { const float d = x[u] - mu; vs += d * d; }
#pragma unroll
  for (int off = 32; off >= 1; off >>= 1) vs += __shfl_xor(vs, off);
  const float var = vs * (1.f / D_) + 1e-5f;
  float rinv = rsqrtf(var);
  rinv = rinv * (1.5f - 0.5f * var * rinv * rinv);   // Newton refine

  const float4 g0 = *(const float4*)(g + c0);
  const float4 g1 = *(const float4*)(g + c0 + 4);
  const float4 b0 = *(const float4*)(bta + c0);
  const float4 b1 = *(const float4*)(bta + c0 + 4);
  float4 o0, o1;
  o0.x = (x[0] - mu) * rinv * g0.x + b0.x;
  o0.y = (x[1] - mu) * rinv * g0.y + b0.y;
  o0.z = (x[2] - mu) * rinv * g0.z + b0.z;
  o0.w = (x[3] - mu) * rinv * g0.w + b0.w;
  o1.x = (x[4] - mu) * rinv * g1.x + b1.x;
  o1.y = (x[5] - mu) * rinv * g1.y + b1.y;
  o1.z = (x[6] - mu) * rinv * g1.z + b1.z;
  o1.w = (x[7] - mu) * rinv * g1.w + b1.w;
  *(float4*)(yrow + c0) = o0;
  *(float4*)(yrow + c0 + 4) = o1;
}

extern "C" void kernel_launch(void* const* d_in, const int* in_sizes, int n_in,
                              void* d_out, int out_size, void* d_ws, size_t ws_size,
                              hipStream_t stream) {
  const float* cur = (const float*)d_in[0];
  const float* lf  = (const float*)d_in[1];
  const float* lw  = (const float*)d_in[2];
  const float* Wq  = (const float*)d_in[3];
  const float* bq  = (const float*)d_in[4];
  const float* Wk  = (const float*)d_in[5];
  const float* bk  = (const float*)d_in[6];
  const float* Wv  = (const float*)d_in[7];
  const float* bv  = (const float*)d_in[8];
  const float* Wo  = (const float*)d_in[9];
  const float* bo  = (const float*)d_in[10];
  const float* adj = (const float*)d_in[11];
  const float* lng = (const float*)d_in[12];
  const float* lnb = (const float*)d_in[13];
  float* out = (float*)d_out;

  const size_t NE = (size_t)BN_ * D_;   // 8388608 elements
  unsigned short* wsb   = (unsigned short*)d_ws;
  unsigned short* curb  = wsb;
  unsigned short* laggb = wsb + NE;
  unsigned short* Qb    = wsb + 2 * NE;
  unsigned short* Kb    = wsb + 3 * NE;
  unsigned short* Vtb   = wsb + 4 * NE;
  unsigned short* attnb = wsb + 5 * NE;
  unsigned short* Wqb   = wsb + 6 * NE;
  unsigned short* Wkb   = Wqb + (size_t)D_ * D_;
  unsigned short* Wvb   = Wkb + (size_t)D_ * D_;
  unsigned short* Wob   = Wvb + (size_t)D_ * D_;
  float*          adjh  = (float*)(Wob + (size_t)D_ * D_);

  prep_kernel<<<8704, 256, 0, stream>>>(lf, lw, cur, adj, laggb, curb, adjh);
  cast_w4_kernel<<<dim3(D_ * D_ / 8 / 256, 4), 256, 0, stream>>>(
      Wq, Wk, Wv, Wo, Wqb, Wkb, Wvb, Wob);

  GJob jq{curb,  Wqb, bq, (void*)Qb,  0, QSCALE_};
  GJob jk{laggb, Wkb, bk, (void*)Kb,  0, 1.0f};
  GJob jv{laggb, Wvb, bv, (void*)Vtb, 1, 1.0f};
  gemm_s_kernel<<<dim3(D_ / 128, BN_ / 128, 3), 256, 0, stream>>>(jq, jk, jv);

  attn_bf16_kernel<<<dim3(N_ / 64, B_ * H_), 256, 0, stream>>>(Qb, Kb, Vtb, adjh, attnb);

  GJob jo{attnb, Wob, bo, (void*)out, 2, 1.0f};
  gemm_s_kernel<<<dim3(D_ / 128, BN_ / 128, 1), 256, 0, stream>>>(jo, jo, jo);

  ln_kernel<<<BN_ / 4, 256, 0, stream>>>(out, cur, lng, lnb);
}